// Round 9
// baseline (237.494 us; speedup 1.0000x reference)
//
#include <hip/hip_runtime.h>

#define VOCAB 8192
#define CTX 4
#define OBLK 8                    // fc_w rows (output columns) per block
#define HALF 4096                 // floats per chunk (half a vocab segment)
#define NCHUNK (OBLK * CTX * 2)   // 64 chunks of 16 KB over this block's 1 MB slice

// Granularity experiment: 512-thread blocks (8 waves), 2 x 16 KB LDS ->
// 4 independent barrier domains per CU (vs 2 x 16-wave before). When one
// block waits at its barrier, three others keep issuing loads -> convoy
// dead-time covered by cross-block TLP. Staging/pipeline/barrier protocol
// identical to the best-known R3 structure (depth-2 register stage, one
// raw lgkm-only barrier per chunk, vmcnt stays counted).
__global__ __launch_bounds__(512, 8) void cbow_kernel(
    const int*   __restrict__ contexts,   // [1024, 4] int32
    const float* __restrict__ fc_w,       // [8192, 32768] row-major f32
    const float* __restrict__ fc_b,       // [8192] f32
    float*       __restrict__ out)        // [1024, 8192] f32
{
    __shared__ float lds[2][HALF];        // 32 KB -> 4 blocks/CU (LDS-wise 5)

    const int t  = threadIdx.x;           // 0..511
    const int o0 = blockIdx.x * OBLK;
    const size_t base = (size_t)o0 * (CTX * VOCAB);  // this block's 1 MB slice

    // Thread t owns batches t and t+512.
    const int4 cv0 = ((const int4*)contexts)[t];
    const int4 cv1 = ((const int4*)contexts)[t + 512];
    const int cA[4] = {cv0.x, cv0.y, cv0.z, cv0.w};
    const int cB[4] = {cv1.x, cv1.y, cv1.z, cv1.w};

    float accA[OBLK], accB[OBLK];
#pragma unroll
    for (int j = 0; j < OBLK; ++j) {
        const float b = fc_b[o0 + j];     // WG-uniform -> scalar load
        accA[j] = b;
        accB[j] = b;
    }

    // Staging: 4096 floats / 512 thr = 2 x float4 per thread.
    // Prologue: chunk 0 -> LDS[0]; chunk 1 -> register stage.
    {
        const float4* s0 = (const float4*)(fc_w + base);
        float4 a = s0[t], b = s0[512 + t];
        float4* dst = (float4*)lds[0];
        dst[t] = a; dst[512 + t] = b;
    }
    const float4* s1 = (const float4*)(fc_w + base + HALF);
    float4 ra = s1[t], rb = s1[512 + t];
    asm volatile("s_waitcnt lgkmcnt(0)\n\ts_barrier" ::: "memory");

    // Chunk k: row j = k>>3, ctx i = (k>>1)&3, half h = k&1; fully unrolled so
    // j/i/h/slot are compile-time. Slice walk is contiguous in fc_w.
    // WAR: write of chunk k+1 lands in the slot whose chunk k-1 gathers all
    // retired at the iter-(k-1) barrier (lgkmcnt(0) drains ds_reads too).
    // vmcnt at ds_write: {k+1: 2 oldest, k+2: 2 newest} -> counted vmcnt(2).
#pragma unroll
    for (int k = 0; k < NCHUNK; ++k) {
        float4 na, nb;
        if (k + 2 < NCHUNK) {             // issue loads for chunk k+2 FIRST
            const float4* src = (const float4*)(fc_w + base + (size_t)(k + 2) * HALF);
            na = src[t]; nb = src[512 + t];
        }
        if (k + 1 < NCHUNK) {             // write chunk k+1 (regs from prev iter)
            float4* dst = (float4*)lds[(k + 1) & 1];
            dst[t] = ra; dst[512 + t] = rb;
        }

        // Masked gathers for chunk k: batch A and batch B, ~50% lanes each.
        {
            const int j = k >> 3, i = (k >> 1) & 3, h = k & 1;
            const int ia = cA[i];
            if ((ia >> 12) == h) accA[j] += lds[k & 1][ia & (HALF - 1)];
            const int ib = cB[i];
            if ((ib >> 12) == h) accB[j] += lds[k & 1][ib & (HALF - 1)];
        }

        ra = na; rb = nb;
        asm volatile("s_waitcnt lgkmcnt(0)\n\ts_barrier" ::: "memory");
    }

    // Epilogue: batch t -> out[t, o0..o0+7] (2 x float4, 32 B), batch t+512 same.
    float4* opA = (float4*)(out + (size_t)t * VOCAB + o0);
    float4* opB = (float4*)(out + (size_t)(t + 512) * VOCAB + o0);
#pragma unroll
    for (int m = 0; m < OBLK / 4; ++m) {
        float4 va, vb;
        va.x = accA[4 * m + 0]; va.y = accA[4 * m + 1];
        va.z = accA[4 * m + 2]; va.w = accA[4 * m + 3];
        vb.x = accB[4 * m + 0]; vb.y = accB[4 * m + 1];
        vb.z = accB[4 * m + 2]; vb.w = accB[4 * m + 3];
        opA[m] = va;
        opB[m] = vb;
    }
}

extern "C" void kernel_launch(void* const* d_in, const int* in_sizes, int n_in,
                              void* d_out, int out_size, void* d_ws, size_t ws_size,
                              hipStream_t stream) {
    const int*   contexts = (const int*)d_in[0];
    const float* fc_w     = (const float*)d_in[1];
    const float* fc_b     = (const float*)d_in[2];
    float*       out      = (float*)d_out;

    dim3 grid(VOCAB / OBLK);   // 1024 blocks, 4 resident per CU
    dim3 block(512);
    cbow_kernel<<<grid, block, 0, stream>>>(contexts, fc_w, fc_b, out);
}

// Round 11
// 210.220 us; speedup vs baseline: 1.1297x; 1.1297x over previous
//
#include <hip/hip_runtime.h>

#define VOCAB 8192
#define CTX 4
#define BATCH 1024
#define OBLK 16                 // fc_w rows (output columns) per workgroup
#define NCHUNK (OBLK * CTX)     // 64 chunks of VOCAB floats each

typedef float vfloat4 __attribute__((ext_vector_type(4)));  // native vec for nt builtins

// R3 structure (best known: 201.6 us) + non-temporal cache policy.
// fc_w is streamed exactly once (zero reuse): `nt` loads skip L2 allocation
// so the stream stops fighting the output writes / tag machinery on every
// XCD. Output stores are nt too (no reader follows). Everything else is
// byte-identical to R3: 2x32 KB LDS double buffer, depth-2 register stage,
// one raw lgkm-only barrier per chunk (vmcnt stays counted across it).
__global__ __launch_bounds__(1024) void cbow_kernel(
    const int*   __restrict__ contexts,   // [1024, 4] int32
    const float* __restrict__ fc_w,       // [8192, 32768] row-major f32
    const float* __restrict__ fc_b,       // [8192] f32
    float*       __restrict__ out)        // [1024, 8192] f32
{
    __shared__ float lds[2][VOCAB];       // 64 KB -> 2 WGs/CU, 32 waves/CU

    const int t  = threadIdx.x;           // == batch index b
    const int o0 = blockIdx.x * OBLK;
    const size_t base = (size_t)o0 * (CTX * VOCAB);  // this WG's contiguous slice

    const int4 cv = ((const int4*)contexts)[t];
    const int cc[4] = {cv.x, cv.y, cv.z, cv.w};

    float acc[OBLK];
#pragma unroll
    for (int j = 0; j < OBLK; ++j) acc[j] = fc_b[o0 + j];

    // Prologue: chunk 0 -> LDS[0]; chunk 1 -> registers (held one iteration).
    {
        const vfloat4* s0 = (const vfloat4*)(fc_w + base);
        vfloat4 a = __builtin_nontemporal_load(s0 + t);
        vfloat4 b = __builtin_nontemporal_load(s0 + 1024 + t);
        vfloat4* dst = (vfloat4*)lds[0];
        dst[t]        = a;
        dst[1024 + t] = b;
    }
    const vfloat4* s1 = (const vfloat4*)(fc_w + base + VOCAB);
    vfloat4 ra = __builtin_nontemporal_load(s1 + t);
    vfloat4 rb = __builtin_nontemporal_load(s1 + 1024 + t);
    asm volatile("s_waitcnt lgkmcnt(0)\n\ts_barrier" ::: "memory");

    // Main loop. Chunk k lives in lds[k&1]; acc row (k>>2), context pos (k&3).
    // Fully unrolled: all acc/cc indices and buffer parity compile-time.
    // WAR: write of chunk k+1 lands in the slot whose chunk k-1 gathers all
    // retired at the iter-(k-1) barrier (lgkmcnt(0) drains ds_reads too).
#pragma unroll
    for (int k = 0; k < NCHUNK; ++k) {
        vfloat4 na, nb;
        if (k + 2 < NCHUNK) {             // issue loads for chunk k+2 FIRST
            const vfloat4* src = (const vfloat4*)(fc_w + base + (size_t)(k + 2) * VOCAB);
            na = __builtin_nontemporal_load(src + t);
            nb = __builtin_nontemporal_load(src + 1024 + t);
        }

        if (k + 1 < NCHUNK) {             // write chunk k+1 (regs from prev iter;
            vfloat4* dst = (vfloat4*)lds[(k + 1) & 1];  // counted vmcnt(2), not 0)
            dst[t]        = ra;
            dst[1024 + t] = rb;
        }

        // Gather chunk k (random-bank ds_read_b32; ~2-way avg conflict: free)
        acc[k >> 2] += lds[k & 1][cc[k & 3]];

        ra = na;
        rb = nb;

        // LDS-only cross-wave hazards: drain lgkmcnt, NOT vmcnt, then barrier.
        if (k < NCHUNK - 1)
            asm volatile("s_waitcnt lgkmcnt(0)\n\ts_barrier" ::: "memory");
    }

    // Epilogue: thread t writes out[t, o0..o0+15] = 64 contiguous bytes
    // (one full cache line, fully written), non-temporal.
    vfloat4* op = (vfloat4*)(out + (size_t)t * VOCAB + o0);
#pragma unroll
    for (int j = 0; j < OBLK / 4; ++j) {
        vfloat4 v;
        v.x = acc[4 * j + 0];
        v.y = acc[4 * j + 1];
        v.z = acc[4 * j + 2];
        v.w = acc[4 * j + 3];
        __builtin_nontemporal_store(v, op + j);
    }
}

extern "C" void kernel_launch(void* const* d_in, const int* in_sizes, int n_in,
                              void* d_out, int out_size, void* d_ws, size_t ws_size,
                              hipStream_t stream) {
    const int*   contexts = (const int*)d_in[0];
    const float* fc_w     = (const float*)d_in[1];
    const float* fc_b     = (const float*)d_in[2];
    float*       out      = (float*)d_out;

    dim3 grid(VOCAB / OBLK);   // 512 workgroups, 2 resident per CU (no tail)
    dim3 block(1024);
    cbow_kernel<<<grid, block, 0, stream>>>(contexts, fc_w, fc_b, out);
}